// Round 1
// baseline (501.606 us; speedup 1.0000x reference)
//
#include <hip/hip_runtime.h>
#include <cstdint>
#include <cstddef>

// ReweightVLAD on MI355X — algebraic collapse of the CRN branch:
//   cw[n,s'] = sum_{c,s} xn[n,c,s]*P[c,s,s'] + t[n,c,s]*Q[c,s,s'] + beta
// where P/Q fold (upsample -> strided conv -> 1x1 accumulation) into fixed
// [C*49, 49] operators built per call.  Then softmax-VLAD in fp32.
// Workspace requirement: ~45 MB of d_ws.

#define N_  512
#define C_  512
#define K_  64
#define S_  49
#define CS_ 25088   // C_*S_

// ---- ws layout (float offsets) ----
#define OFF_MU      0u
#define OFF_RSTD    262144u
#define OFF_RN      524288u
#define OFF_WBS     549376u
#define OFF_WBM     553984u
#define OFF_WBL     579072u
#define OFF_WBT     620544u
#define OFF_BETA    653312u
#define OFF_P       653328u
#define OFF_Q       1882640u
#define OFF_CWPART  3111952u   // 256*512*49
#define OFF_CW      9534480u
#define OFF_WR      9559568u
#define OFF_WSUM    11165200u
// total = 11197968 floats = 44.8 MB

__device__ __forceinline__ float wave_sum64(float v) {
  #pragma unroll
  for (int off = 32; off; off >>= 1) v += __shfl_xor(v, off, 64);
  return v;
}
__device__ __forceinline__ float wave_max64(float v) {
  #pragma unroll
  for (int off = 32; off; off >>= 1) v = fmaxf(v, __shfl_xor(v, off, 64));
  return v;
}

// bilinear align_corners 7->20 matrix entry, matches np float semantics
__device__ __forceinline__ float m20val(int r, int p) {
  float pos = (float)(r * 6) / 19.0f;   // exact at r=0,19
  int lo = (int)floorf(pos);
  int hi = min(lo + 1, 6);
  float fr = pos - (float)lo;
  float v = 0.f;
  if (p == lo) v += 1.f - fr;
  if (p == hi) v += fr;
  return v;
}

// -------- 1. LayerNorm stats per (n,c) over 49 elems --------
__global__ void k_ln_stats(const float* __restrict__ x, float* __restrict__ mu,
                           float* __restrict__ rstd) {
  int idx = blockIdx.x * 256 + threadIdx.x;     // [0, 262144)
  const float* p = x + (size_t)idx * S_;
  float s = 0.f, s2 = 0.f;
  #pragma unroll
  for (int i = 0; i < S_; ++i) { float v = p[i]; s += v; s2 = fmaf(v, v, s2); }
  float m = s * (1.f / 49.f);
  float var = s2 * (1.f / 49.f) - m * m;
  mu[idx] = m;
  rstd[idx] = 1.f / sqrtf(var + 1e-5f);
}

// -------- 2. per-(n,s) inverse channel L2 norm --------
__global__ void k_rn(const float* __restrict__ x, float* __restrict__ rn) {
  __shared__ float part[5][49];
  int n = blockIdx.x, t = threadIdx.x;
  int r = t / 49, s = t % 49;
  if (t < 245) {
    float acc = 0.f;
    for (int c = r; c < 512; c += 5) {
      float v = x[(size_t)n * CS_ + (size_t)c * 49 + s];
      acc = fmaf(v, v, acc);
    }
    part[r][s] = acc;
  }
  __syncthreads();
  if (t < 49) {
    float sum = part[0][t] + part[1][t] + part[2][t] + part[3][t] + part[4][t];
    rn[n * 49 + t] = 1.f / fmaxf(sqrtf(sum), 1e-12f);
  }
}

// -------- 3. fold acc_w into conv weights; beta scalar --------
__global__ void k_wbar(const float* __restrict__ w_s, const float* __restrict__ w_m,
                       const float* __restrict__ w_l, const float* __restrict__ w_t,
                       const float* __restrict__ accw, const float* __restrict__ accb,
                       const float* __restrict__ b_s, const float* __restrict__ b_m,
                       const float* __restrict__ b_l, const float* __restrict__ b_t,
                       float* __restrict__ wbs, float* __restrict__ wbm,
                       float* __restrict__ wbl, float* __restrict__ wbt,
                       float* __restrict__ beta) {
  int id = blockIdx.x * 256 + threadIdx.x;      // [0, 103936) exact
  if (id == 0) {
    float b = accb[0];
    for (int o = 0; o < 32; ++o) b = fmaf(accw[o],      b_s[o], b);
    for (int o = 0; o < 32; ++o) b = fmaf(accw[32 + o], b_m[o], b);
    for (int o = 0; o < 20; ++o) b = fmaf(accw[64 + o], b_l[o], b);
    for (int o = 0; o < 16; ++o) b = fmaf(accw[84 + o], b_t[o], b);
    beta[0] = b;
  }
  if (id < 4608) {                 // xs 3x3
    int c = id / 9, uv = id % 9;
    float a = 0.f;
    for (int o = 0; o < 32; ++o) a = fmaf(accw[o], w_s[(size_t)(o * 512 + c) * 9 + uv], a);
    wbs[id] = a;
  } else if (id < 29696) {         // xm 7x7
    int i2 = id - 4608; int c = i2 / 49, uv = i2 % 49;
    float a = 0.f;
    for (int o = 0; o < 32; ++o) a = fmaf(accw[32 + o], w_m[(size_t)(o * 512 + c) * 49 + uv], a);
    wbm[i2] = a;
  } else if (id < 71168) {         // xl 9x9
    int i2 = id - 29696; int c = i2 / 81, uv = i2 % 81;
    float a = 0.f;
    for (int o = 0; o < 20; ++o) a = fmaf(accw[64 + o], w_l[(size_t)(o * 512 + c) * 81 + uv], a);
    wbl[i2] = a;
  } else {                         // tc 8x8
    int i2 = id - 71168; int c = i2 / 64, uv = i2 % 64;
    float a = 0.f;
    for (int o = 0; o < 16; ++o) a = fmaf(accw[84 + o], w_t[(size_t)(o * 512 + c) * 64 + uv], a);
    wbt[i2] = a;
  }
}

// -------- 4. build P[c,s,s'] and Q[c,s,s'] --------
__global__ void k_buildP(const float* __restrict__ wbs, const float* __restrict__ wbm,
                         const float* __restrict__ wbl, const float* __restrict__ wbt,
                         float* __restrict__ P, float* __restrict__ Q) {
  __shared__ float M[20][7];
  int t = threadIdx.x;
  if (t < 140) { int r = t / 7, p = t % 7; M[r][p] = m20val(r, p); }
  __syncthreads();
  int idx = blockIdx.x * 256 + t;               // [0, 1229312) exact
  int sp = idx % 49; int rest = idx / 49; int s = rest % 49; int c = rest / 49;
  int i = sp / 7, j = sp % 7, pp = s / 7, qq = s % 7;

  float sumP = 0.f;
  { // xs: 3x3, stride 3, pad 1
    float rv[3];
    #pragma unroll
    for (int v = 0; v < 3; ++v) { int col = j * 3 - 1 + v; rv[v] = ((unsigned)col < 20u) ? M[col][qq] : 0.f; }
    const float* wb = wbs + c * 9;
    #pragma unroll
    for (int u = 0; u < 3; ++u) {
      int row = i * 3 - 1 + u; float ru = ((unsigned)row < 20u) ? M[row][pp] : 0.f;
      float a = wb[u * 3 + 0] * rv[0];
      a = fmaf(wb[u * 3 + 1], rv[1], a);
      a = fmaf(wb[u * 3 + 2], rv[2], a);
      sumP = fmaf(ru, a, sumP);
    }
  }
  { // xm: 7x7, stride 5, pad 9
    float rv[7];
    #pragma unroll
    for (int v = 0; v < 7; ++v) { int col = j * 5 - 9 + v; rv[v] = ((unsigned)col < 20u) ? M[col][qq] : 0.f; }
    const float* wb = wbm + c * 49;
    #pragma unroll
    for (int u = 0; u < 7; ++u) {
      int row = i * 5 - 9 + u; float ru = ((unsigned)row < 20u) ? M[row][pp] : 0.f;
      float a = 0.f;
      #pragma unroll
      for (int v = 0; v < 7; ++v) a = fmaf(wb[u * 7 + v], rv[v], a);
      sumP = fmaf(ru, a, sumP);
    }
  }
  { // xl: 9x9, stride 2, pad 1
    float rv[9];
    #pragma unroll
    for (int v = 0; v < 9; ++v) { int col = j * 2 - 1 + v; rv[v] = ((unsigned)col < 20u) ? M[col][qq] : 0.f; }
    const float* wb = wbl + c * 81;
    #pragma unroll
    for (int u = 0; u < 9; ++u) {
      int row = i * 2 - 1 + u; float ru = ((unsigned)row < 20u) ? M[row][pp] : 0.f;
      float a = 0.f;
      #pragma unroll
      for (int v = 0; v < 9; ++v) a = fmaf(wb[u * 9 + v], rv[v], a);
      sumP = fmaf(ru, a, sumP);
    }
  }
  P[idx] = sumP;

  float sumQ = 0.f;
  { // tc: 8x8, stride 2, pad 0
    float rv[8];
    #pragma unroll
    for (int v = 0; v < 8; ++v) { int col = j * 2 + v; rv[v] = ((unsigned)col < 20u) ? M[col][qq] : 0.f; }
    const float* wb = wbt + c * 64;
    #pragma unroll
    for (int u = 0; u < 8; ++u) {
      int row = i * 2 + u; float ru = ((unsigned)row < 20u) ? M[row][pp] : 0.f;
      float a = 0.f;
      #pragma unroll
      for (int v = 0; v < 8; ++v) a = fmaf(wb[u * 8 + v], rv[v], a);
      sumQ = fmaf(ru, a, sumQ);
    }
  }
  Q[idx] = sumQ;
}

// -------- 5. cw split-K GEMM: lane=n, 49 accs in regs, P via uniform loads --------
__global__ void __launch_bounds__(256) k_cw(
    const float* __restrict__ x, const float* __restrict__ tin,
    const float* __restrict__ mu, const float* __restrict__ rstd,
    const float* __restrict__ lnw, const float* __restrict__ lnb,
    const float* __restrict__ P, const float* __restrict__ Q,
    float* __restrict__ cwpart) {
  int bx = blockIdx.x;                 // [0,512)
  int ks = bx & 255, nt = bx >> 8;
  int n = nt * 256 + threadIdx.x;
  bool isT = ks >= 128;
  int c0 = (isT ? ks - 128 : ks) * 4;  // 4 channels per split
  const float* src = isT ? tin : x;
  const float* mat = isT ? Q : P;

  float acc[49];
  #pragma unroll
  for (int q = 0; q < 49; ++q) acc[q] = 0.f;

  for (int ci = 0; ci < 4; ++ci) {
    int c = c0 + ci;
    const float* xp = src + (size_t)n * CS_ + (size_t)c * 49;
    float xr[49];
    #pragma unroll
    for (int q = 0; q < 49; ++q) xr[q] = xp[q];
    if (!isT) {
      float m = mu[n * 512 + c], r = rstd[n * 512 + c];
      #pragma unroll
      for (int q = 0; q < 49; ++q) xr[q] = fmaf((xr[q] - m) * r, lnw[q], lnb[q]);
    }
    const float* prow = mat + (size_t)c * (49 * 49);
    #pragma unroll 1
    for (int s = 0; s < 49; ++s) {
      float xv = xr[s];
      const float* pr = prow + s * 49;   // wave-uniform -> scalar loads
      #pragma unroll
      for (int q = 0; q < 49; ++q) acc[q] = fmaf(xv, pr[q], acc[q]);
    }
  }
  float* o = cwpart + ((size_t)ks * 512 + n) * 49;
  #pragma unroll
  for (int q = 0; q < 49; ++q) o[q] = acc[q];
}

// -------- 6. reduce split-K partials --------
__global__ void k_cwreduce(const float* __restrict__ cwpart, const float* __restrict__ beta,
                           float* __restrict__ cw) {
  int idx = blockIdx.x * 256 + threadIdx.x;     // [0, 25088) exact
  float s = beta[0];
  for (int ks = 0; ks < 256; ++ks) s += cwpart[(size_t)ks * 25088 + idx];
  cw[idx] = s;
}

// -------- 7. logits + softmax + reweight: lane=k, block=n --------
__global__ void __launch_bounds__(256) k_logits(
    const float* __restrict__ x, const float* __restrict__ convw,
    const float* __restrict__ convb, const float* __restrict__ rn,
    const float* __restrict__ cw, float* __restrict__ wr,
    float* __restrict__ wsum) {
  __shared__ float part[3][64][53];
  int n = blockIdx.x;
  int wu = __builtin_amdgcn_readfirstlane((int)(threadIdx.x >> 6));
  int k = threadIdx.x & 63;

  float acc[49];
  #pragma unroll
  for (int s = 0; s < 49; ++s) acc[s] = 0.f;

  const float* xbase = x + (size_t)n * CS_;
  for (int c4 = 0; c4 < 128; c4 += 4) {
    int c = wu * 128 + c4;
    float4 wv4 = *reinterpret_cast<const float4*>(&convw[(size_t)k * 512 + c]);
    float wvv[4] = {wv4.x, wv4.y, wv4.z, wv4.w};
    #pragma unroll
    for (int d = 0; d < 4; ++d) {
      const float* xp = xbase + (size_t)(c + d) * 49;  // uniform -> scalar loads
      float wv = wvv[d];
      #pragma unroll
      for (int s = 0; s < 49; ++s) acc[s] = fmaf(wv, xp[s], acc[s]);
    }
  }
  if (wu > 0) {
    #pragma unroll
    for (int s = 0; s < 49; ++s) part[wu - 1][k][s] = acc[s];
  }
  __syncthreads();
  if (wu == 0) {
    #pragma unroll
    for (int s = 0; s < 49; ++s) acc[s] += part[0][k][s] + part[1][k][s] + part[2][k][s];
    float wsp = 0.f;
    const float* rnp = rn + n * 49;
    const float* cwp = cw + n * 49;
    float cb = convb[k];
    for (int s = 0; s < 49; ++s) {
      float lg = fmaf(acc[s], rnp[s], cb);
      float mx = wave_max64(lg);
      float e = expf(lg - mx);               // underflow->0 matches reference
      float sm = wave_sum64(e);
      float sa = e / sm;
      float wv = sa * cwp[s];
      wr[((size_t)n * 64 + k) * 49 + s] = wv * rnp[s];  // fold rn for vlad
      wsp += wv;
    }
    wsum[n * 64 + k] = wsp;
  }
}

// -------- 8. VLAD aggregate + intra-norm + global-norm: block=n, lane=c --------
__global__ void __launch_bounds__(256) k_vlad(
    const float* __restrict__ x, const float* __restrict__ wr,
    const float* __restrict__ wsum, const float* __restrict__ cent,
    float* __restrict__ out) {
  __shared__ float vnp[4][64];
  __shared__ float scal[64];
  int n = blockIdx.x;
  int wv = threadIdx.x >> 6, lane = threadIdx.x & 63;
  const float* wrbase = wr + (size_t)n * 3136;
  const float* wsbase = wsum + n * 64;
  float* obase = out + (size_t)n * 32768;

  for (int chunk = 0; chunk < 2; ++chunk) {
    int c = chunk * 256 + wv * 64 + lane;
    const float* xp = x + (size_t)n * CS_ + (size_t)c * 49;
    float xr[49];
    #pragma unroll
    for (int s = 0; s < 49; ++s) xr[s] = xp[s];
    #pragma unroll 1
    for (int k = 0; k < 64; ++k) {
      const float* wp = wrbase + k * 49;     // uniform -> scalar loads
      float d0 = 0.f, d1 = 0.f, d2 = 0.f, d3 = 0.f;
      #pragma unroll
      for (int s = 0; s < 48; s += 4) {
        d0 = fmaf(wp[s],     xr[s],     d0);
        d1 = fmaf(wp[s + 1], xr[s + 1], d1);
        d2 = fmaf(wp[s + 2], xr[s + 2], d2);
        d3 = fmaf(wp[s + 3], xr[s + 3], d3);
      }
      d0 = fmaf(wp[48], xr[48], d0);
      float val = (d0 + d1) + (d2 + d3);
      val = fmaf(-cent[(size_t)k * 512 + c], wsbase[k], val);
      obase[(size_t)k * 512 + c] = val;
      float red = wave_sum64(val * val);
      if (lane == 0) {
        if (chunk == 0) vnp[wv][k] = red; else vnp[wv][k] += red;
      }
    }
  }
  __syncthreads();
  if (threadIdx.x < 64) {
    int k = threadIdx.x;
    float v2 = vnp[0][k] + vnp[1][k] + vnp[2][k] + vnp[3][k];
    float vn = sqrtf(v2);
    float den = fmaxf(vn, 1e-12f);
    float cr = vn / den; cr *= cr;            // (vn/max(vn,eps))^2
    float g = wave_sum64(cr);
    scal[k] = 1.f / (den * fmaxf(sqrtf(g), 1e-12f));
  }
  __syncthreads();
  for (int idx = (int)threadIdx.x; idx < 32768; idx += 256) {
    obase[idx] *= scal[idx >> 9];
  }
}

extern "C" void kernel_launch(void* const* d_in, const int* in_sizes, int n_in,
                              void* d_out, int out_size, void* d_ws, size_t ws_size,
                              hipStream_t stream) {
  const float* x     = (const float*)d_in[0];
  const float* t     = (const float*)d_in[1];
  const float* cent  = (const float*)d_in[2];
  const float* convw = (const float*)d_in[3];
  const float* convb = (const float*)d_in[4];
  const float* lnw   = (const float*)d_in[5];
  const float* lnb   = (const float*)d_in[6];
  const float* w_t   = (const float*)d_in[7];
  const float* b_t   = (const float*)d_in[8];
  const float* w_s   = (const float*)d_in[9];
  const float* b_s   = (const float*)d_in[10];
  const float* w_m   = (const float*)d_in[11];
  const float* b_m   = (const float*)d_in[12];
  const float* w_l   = (const float*)d_in[13];
  const float* b_l   = (const float*)d_in[14];
  const float* accw  = (const float*)d_in[15];
  const float* accb  = (const float*)d_in[16];
  float* ws  = (float*)d_ws;
  float* out = (float*)d_out;

  float* mu     = ws + OFF_MU;
  float* rstd   = ws + OFF_RSTD;
  float* rn     = ws + OFF_RN;
  float* wbs    = ws + OFF_WBS;
  float* wbm    = ws + OFF_WBM;
  float* wbl    = ws + OFF_WBL;
  float* wbt    = ws + OFF_WBT;
  float* beta   = ws + OFF_BETA;
  float* P      = ws + OFF_P;
  float* Q      = ws + OFF_Q;
  float* cwpart = ws + OFF_CWPART;
  float* cw     = ws + OFF_CW;
  float* wr     = ws + OFF_WR;
  float* wsumb  = ws + OFF_WSUM;

  k_ln_stats<<<dim3(1024), dim3(256), 0, stream>>>(x, mu, rstd);
  k_rn<<<dim3(512), dim3(256), 0, stream>>>(x, rn);
  k_wbar<<<dim3(406), dim3(256), 0, stream>>>(w_s, w_m, w_l, w_t, accw, accb,
                                              b_s, b_m, b_l, b_t,
                                              wbs, wbm, wbl, wbt, beta);
  k_buildP<<<dim3(4802), dim3(256), 0, stream>>>(wbs, wbm, wbl, wbt, P, Q);
  k_cw<<<dim3(512), dim3(256), 0, stream>>>(x, t, mu, rstd, lnw, lnb, P, Q, cwpart);
  k_cwreduce<<<dim3(98), dim3(256), 0, stream>>>(cwpart, beta, cw);
  k_logits<<<dim3(512), dim3(256), 0, stream>>>(x, convw, convb, rn, cw, wr, wsumb);
  k_vlad<<<dim3(512), dim3(256), 0, stream>>>(x, wr, wsumb, cent, out);
}

// Round 3
// 456.928 us; speedup vs baseline: 1.0978x; 1.0978x over previous
//
#include <hip/hip_runtime.h>
#include <cstdint>
#include <cstddef>

// ReweightVLAD on MI355X — CRN collapsed to cw = xn·P + t·Q + beta with
// P,Q [C*49,49] built per call; softmax-VLAD fp32.
// Round 3: fix k_rn channel-loop trip count (103, not 102 — channels 510/511
// were dropped from the L2 norm, absmax 2.7e-2). No other changes vs round 2.

#define N_  512
#define C_  512
#define K_  64
#define S_  49
#define CS_ 25088   // C_*S_

// ---- ws layout (float offsets) ----
#define OFF_RN      0u
#define OFF_WBS     25088u
#define OFF_WBM     29696u
#define OFF_WBL     54784u
#define OFF_WBT     96256u
#define OFF_BETA    129024u
#define OFF_P       129040u
#define OFF_Q       1358352u
#define OFF_CWPART  2587664u   // 256*512*49
#define OFF_WR      9010192u
#define OFF_WSUM    10615824u
// total = 10648592 floats = 42.6 MB

__device__ __forceinline__ float wave_sum64(float v) {
  #pragma unroll
  for (int off = 32; off; off >>= 1) v += __shfl_xor(v, off, 64);
  return v;
}

// bilinear align_corners 7->20 matrix entry
__device__ __forceinline__ float m20val(int r, int p) {
  float pos = (float)(r * 6) / 19.0f;
  int lo = (int)floorf(pos);
  int hi = min(lo + 1, 6);
  float fr = pos - (float)lo;
  float v = 0.f;
  if (p == lo) v += 1.f - fr;
  if (p == hi) v += fr;
  return v;
}

// -------- 1. per-(n,s) inverse channel L2 norm --------
__global__ void k_rn(const float* __restrict__ x, float* __restrict__ rn) {
  __shared__ float part[5][49];
  int n = blockIdx.x, t = threadIdx.x;
  int r = t / 49, s = t % 49;
  if (t < 245) {
    float acc = 0.f;
    #pragma unroll 4
    for (int ci = 0; ci < 103; ++ci) {      // ceil(512/5)=103 (was 102: dropped c=510,511)
      int c = r + ci * 5;
      if (c < 512) {
        float v = x[(size_t)n * CS_ + (size_t)c * 49 + s];
        acc = fmaf(v, v, acc);
      }
    }
    part[r][s] = acc;
  }
  __syncthreads();
  if (t < 49) {
    float sum = part[0][t] + part[1][t] + part[2][t] + part[3][t] + part[4][t];
    rn[n * 49 + t] = 1.f / fmaxf(sqrtf(sum), 1e-12f);
  }
}

// -------- 2. fold acc_w into conv weights; beta scalar --------
__global__ void k_wbar(const float* __restrict__ w_s, const float* __restrict__ w_m,
                       const float* __restrict__ w_l, const float* __restrict__ w_t,
                       const float* __restrict__ accw, const float* __restrict__ accb,
                       const float* __restrict__ b_s, const float* __restrict__ b_m,
                       const float* __restrict__ b_l, const float* __restrict__ b_t,
                       float* __restrict__ wbs, float* __restrict__ wbm,
                       float* __restrict__ wbl, float* __restrict__ wbt,
                       float* __restrict__ beta) {
  int id = blockIdx.x * 256 + threadIdx.x;      // [0, 103936) exact
  if (id == 0) {
    float b = accb[0];
    for (int o = 0; o < 32; ++o) b = fmaf(accw[o],      b_s[o], b);
    for (int o = 0; o < 32; ++o) b = fmaf(accw[32 + o], b_m[o], b);
    for (int o = 0; o < 20; ++o) b = fmaf(accw[64 + o], b_l[o], b);
    for (int o = 0; o < 16; ++o) b = fmaf(accw[84 + o], b_t[o], b);
    beta[0] = b;
  }
  if (id < 4608) {                 // xs 3x3
    int c = id / 9, uv = id % 9;
    float a = 0.f;
    for (int o = 0; o < 32; ++o) a = fmaf(accw[o], w_s[(size_t)(o * 512 + c) * 9 + uv], a);
    wbs[id] = a;
  } else if (id < 29696) {         // xm 7x7
    int i2 = id - 4608; int c = i2 / 49, uv = i2 % 49;
    float a = 0.f;
    for (int o = 0; o < 32; ++o) a = fmaf(accw[32 + o], w_m[(size_t)(o * 512 + c) * 49 + uv], a);
    wbm[i2] = a;
  } else if (id < 71168) {         // xl 9x9
    int i2 = id - 29696; int c = i2 / 81, uv = i2 % 81;
    float a = 0.f;
    for (int o = 0; o < 20; ++o) a = fmaf(accw[64 + o], w_l[(size_t)(o * 512 + c) * 81 + uv], a);
    wbl[i2] = a;
  } else {                         // tc 8x8
    int i2 = id - 71168; int c = i2 / 64, uv = i2 % 64;
    float a = 0.f;
    for (int o = 0; o < 16; ++o) a = fmaf(accw[84 + o], w_t[(size_t)(o * 512 + c) * 64 + uv], a);
    wbt[i2] = a;
  }
}

// -------- 3. build P[c,s,s'] and Q[c,s,s'] --------
__global__ void k_buildP(const float* __restrict__ wbs, const float* __restrict__ wbm,
                         const float* __restrict__ wbl, const float* __restrict__ wbt,
                         float* __restrict__ P, float* __restrict__ Q) {
  __shared__ float M[20][7];
  int t = threadIdx.x;
  if (t < 140) { int r = t / 7, p = t % 7; M[r][p] = m20val(r, p); }
  __syncthreads();
  int idx = blockIdx.x * 256 + t;               // [0, 1229312) exact
  int sp = idx % 49; int rest = idx / 49; int s = rest % 49; int c = rest / 49;
  int i = sp / 7, j = sp % 7, pp = s / 7, qq = s % 7;

  float sumP = 0.f;
  { // xs: 3x3, stride 3, pad 1
    float rv[3];
    #pragma unroll
    for (int v = 0; v < 3; ++v) { int col = j * 3 - 1 + v; rv[v] = ((unsigned)col < 20u) ? M[col][qq] : 0.f; }
    const float* wb = wbs + c * 9;
    #pragma unroll
    for (int u = 0; u < 3; ++u) {
      int row = i * 3 - 1 + u; float ru = ((unsigned)row < 20u) ? M[row][pp] : 0.f;
      float a = wb[u * 3 + 0] * rv[0];
      a = fmaf(wb[u * 3 + 1], rv[1], a);
      a = fmaf(wb[u * 3 + 2], rv[2], a);
      sumP = fmaf(ru, a, sumP);
    }
  }
  { // xm: 7x7, stride 5, pad 9
    float rv[7];
    #pragma unroll
    for (int v = 0; v < 7; ++v) { int col = j * 5 - 9 + v; rv[v] = ((unsigned)col < 20u) ? M[col][qq] : 0.f; }
    const float* wb = wbm + c * 49;
    #pragma unroll
    for (int u = 0; u < 7; ++u) {
      int row = i * 5 - 9 + u; float ru = ((unsigned)row < 20u) ? M[row][pp] : 0.f;
      float a = 0.f;
      #pragma unroll
      for (int v = 0; v < 7; ++v) a = fmaf(wb[u * 7 + v], rv[v], a);
      sumP = fmaf(ru, a, sumP);
    }
  }
  { // xl: 9x9, stride 2, pad 1
    float rv[9];
    #pragma unroll
    for (int v = 0; v < 9; ++v) { int col = j * 2 - 1 + v; rv[v] = ((unsigned)col < 20u) ? M[col][qq] : 0.f; }
    const float* wb = wbl + c * 81;
    #pragma unroll
    for (int u = 0; u < 9; ++u) {
      int row = i * 2 - 1 + u; float ru = ((unsigned)row < 20u) ? M[row][pp] : 0.f;
      float a = 0.f;
      #pragma unroll
      for (int v = 0; v < 9; ++v) a = fmaf(wb[u * 9 + v], rv[v], a);
      sumP = fmaf(ru, a, sumP);
    }
  }
  P[idx] = sumP;

  float sumQ = 0.f;
  { // tc: 8x8, stride 2, pad 0
    float rv[8];
    #pragma unroll
    for (int v = 0; v < 8; ++v) { int col = j * 2 + v; rv[v] = ((unsigned)col < 20u) ? M[col][qq] : 0.f; }
    const float* wb = wbt + c * 64;
    #pragma unroll
    for (int u = 0; u < 8; ++u) {
      int row = i * 2 + u; float ru = ((unsigned)row < 20u) ? M[row][pp] : 0.f;
      float a = 0.f;
      #pragma unroll
      for (int v = 0; v < 8; ++v) a = fmaf(wb[u * 8 + v], rv[v], a);
      sumQ = fmaf(ru, a, sumQ);
    }
  }
  Q[idx] = sumQ;
}

// -------- 4. cw split-K GEMM with inline LN stats; q-split x2 --------
// grid 1024: ks = bx&255 (x:0-127 c-quads, t:128-255), qh = (bx>>8)&1, nt = bx>>9
__global__ void __launch_bounds__(256) k_cw(
    const float* __restrict__ x, const float* __restrict__ tin,
    const float* __restrict__ lnw, const float* __restrict__ lnb,
    const float* __restrict__ P, const float* __restrict__ Q,
    float* __restrict__ cwpart) {
  int bx = blockIdx.x;
  int ks = bx & 255, qh = (bx >> 8) & 1, nt = bx >> 9;
  int n = nt * 256 + threadIdx.x;
  bool isT = ks >= 128;
  int c0 = (ks & 127) * 4;
  const float* src = isT ? tin : x;
  const float* mat = isT ? Q : P;
  int q0 = qh * 24;     // q in [0,25) or [24,49); q=24 written twice, identical bits

  float acc[25];
  #pragma unroll
  for (int i = 0; i < 25; ++i) acc[i] = 0.f;

  for (int ci = 0; ci < 4; ++ci) {
    int c = c0 + ci;
    const float* xp = src + (size_t)n * CS_ + (size_t)c * 49;
    const float* prow = mat + (size_t)c * 2401 + q0;
    if (!isT) {
      float s1 = 0.f, s2 = 0.f;
      #pragma unroll
      for (int s = 0; s < 49; ++s) { float v = xp[s]; s1 += v; s2 = fmaf(v, v, s2); }
      float m = s1 * (1.f / 49.f);
      float var = s2 * (1.f / 49.f) - m * m;
      float r = 1.f / sqrtf(var + 1e-5f);
      #pragma unroll 7
      for (int s = 0; s < 49; ++s) {
        float xv = fmaf((xp[s] - m) * r, lnw[s], lnb[s]);
        const float* pr = prow + s * 49;
        #pragma unroll
        for (int i = 0; i < 25; ++i) acc[i] = fmaf(xv, pr[i], acc[i]);
      }
    } else {
      #pragma unroll 7
      for (int s = 0; s < 49; ++s) {
        float xv = xp[s];
        const float* pr = prow + s * 49;
        #pragma unroll
        for (int i = 0; i < 25; ++i) acc[i] = fmaf(xv, pr[i], acc[i]);
      }
    }
  }
  float* o = cwpart + ((size_t)ks * 512 + n) * 49 + q0;
  #pragma unroll
  for (int i = 0; i < 25; ++i) o[i] = acc[i];
}

// -------- 5. logits + softmax + reweight (block=n) --------
__global__ void __launch_bounds__(256) k_logits(
    const float* __restrict__ x, const float* __restrict__ convw,
    const float* __restrict__ convb, const float* __restrict__ rn,
    const float* __restrict__ cwpart, const float* __restrict__ beta,
    float* __restrict__ wr, float* __restrict__ wsum) {
  __shared__ float part[4 * 64 * 49];   // 50176 B; reused as wsp in phase 2c
  __shared__ float cw4[4 * 49];
  __shared__ float mx4[4 * 49];
  __shared__ float sm4[4 * 49];
  int n = blockIdx.x;
  int tid = threadIdx.x;
  int wu = tid >> 6, k = tid & 63;

  // phase 0: cw split-K reduction (196 threads, coalesced 196B rows)
  if (tid < 196) {
    int s = tid % 49, g = tid / 49;
    const float* cp = cwpart + (size_t)(g * 64) * 25088 + (size_t)n * 49 + s;
    float a = 0.f;
    #pragma unroll 8
    for (int i = 0; i < 64; ++i) a += cp[(size_t)i * 25088];
    cw4[g * 49 + s] = a;
  }

  // phase 1: logits GEMM, wave wu covers c in [wu*128, wu*128+128), lane = k
  float acc[49];
  #pragma unroll
  for (int s = 0; s < 49; ++s) acc[s] = 0.f;
  const float* xbase = x + (size_t)n * CS_ + (size_t)wu * (128 * 49);
  const float* wbase = convw + (size_t)k * 512 + wu * 128;
  #pragma unroll 1
  for (int c4 = 0; c4 < 128; c4 += 4) {
    float4 wv4 = *reinterpret_cast<const float4*>(wbase + c4);
    float wvv[4] = {wv4.x, wv4.y, wv4.z, wv4.w};
    #pragma unroll
    for (int d = 0; d < 4; ++d) {
      const float* xp = xbase + (size_t)(c4 + d) * 49;   // wave-uniform -> s_load
      float wv = wvv[d];
      #pragma unroll
      for (int s = 0; s < 49; ++s) acc[s] = fmaf(wv, xp[s], acc[s]);
    }
  }
  {
    float* pp = part + (size_t)(wu * 64 + k) * 49;
    #pragma unroll
    for (int s = 0; s < 49; ++s) pp[s] = acc[s];
  }
  __syncthreads();

  // phase 2: softmax over k, thread = (sg, s), 16 k's each
  float lg[16];
  int sg = tid / 49, s_ = tid % 49;
  float rnv = 0.f;
  if (tid < 196) {
    rnv = rn[n * 49 + s_];
    float mloc = -1e30f;
    #pragma unroll
    for (int kk = 0; kk < 16; ++kk) {
      int kq = sg * 16 + kk;
      float a = part[(0 * 64 + kq) * 49 + s_] + part[(1 * 64 + kq) * 49 + s_]
              + part[(2 * 64 + kq) * 49 + s_] + part[(3 * 64 + kq) * 49 + s_];
      lg[kk] = fmaf(a, rnv, convb[kq]);
      mloc = fmaxf(mloc, lg[kk]);
    }
    mx4[sg * 49 + s_] = mloc;
  }
  __syncthreads();
  if (tid < 196) {
    float m0 = fmaxf(fmaxf(mx4[s_], mx4[49 + s_]), fmaxf(mx4[98 + s_], mx4[147 + s_]));
    float sloc = 0.f;
    #pragma unroll
    for (int kk = 0; kk < 16; ++kk) { lg[kk] = expf(lg[kk] - m0); sloc += lg[kk]; }
    sm4[sg * 49 + s_] = sloc;
  }
  __syncthreads();
  if (tid < 196) {
    float ssum = sm4[s_] + sm4[49 + s_] + sm4[98 + s_] + sm4[147 + s_];
    float cwv = cw4[s_] + cw4[49 + s_] + cw4[98 + s_] + cw4[147 + s_] + beta[0];
    float inv = cwv / ssum;        // wv = e * (cw/sum)
    float wrs = inv * rnv;
    #pragma unroll
    for (int kk = 0; kk < 16; ++kk) {
      int kq = sg * 16 + kk;
      wr[((size_t)n * 64 + kq) * 49 + s_] = lg[kk] * wrs;  // coalesced 196B rows
      part[kq * 49 + s_] = lg[kk] * inv;                   // wsp for wsum
    }
  }
  __syncthreads();
  if (tid < 64) {
    float a = 0.f;
    #pragma unroll 7
    for (int s = 0; s < 49; ++s) a += part[tid * 49 + s];
    wsum[n * 64 + tid] = a;
  }
}

// -------- 6. VLAD + intra-norm + global-norm, single output write --------
__global__ void __launch_bounds__(512, 2) k_vlad(
    const float* __restrict__ x, const float* __restrict__ wr,
    const float* __restrict__ wsum, const float* __restrict__ cent,
    float* __restrict__ out) {
  __shared__ float ssq[8][64];
  __shared__ float scal[64];
  int n = blockIdx.x;
  int c = threadIdx.x;                 // 0..511
  int wv = c >> 6, lane = c & 63;
  const float* xp = x + (size_t)n * CS_ + (size_t)c * 49;
  float xr[49];
  #pragma unroll
  for (int s = 0; s < 49; ++s) xr[s] = xp[s];
  const float* wrb = wr + (size_t)n * 3136;    // wave-uniform -> s_load
  const float* wsb = wsum + n * 64;
  const float* cb = cent + c;

  float val[64];
  #pragma unroll
  for (int k = 0; k < 64; ++k) {
    const float* wp = wrb + k * 49;
    float d0 = 0.f, d1 = 0.f, d2 = 0.f, d3 = 0.f;
    #pragma unroll
    for (int s = 0; s < 48; s += 4) {
      d0 = fmaf(wp[s],     xr[s],     d0);
      d1 = fmaf(wp[s + 1], xr[s + 1], d1);
      d2 = fmaf(wp[s + 2], xr[s + 2], d2);
      d3 = fmaf(wp[s + 3], xr[s + 3], d3);
    }
    d0 = fmaf(wp[48], xr[48], d0);
    float v = (d0 + d1) + (d2 + d3);
    val[k] = fmaf(-cb[(size_t)k * 512], wsb[k], v);
  }
  #pragma unroll
  for (int k = 0; k < 64; ++k) {
    float r2 = wave_sum64(val[k] * val[k]);
    if (lane == 0) ssq[wv][k] = r2;
  }
  __syncthreads();
  if (threadIdx.x < 64) {
    int k = threadIdx.x;
    float v2 = 0.f;
    #pragma unroll
    for (int w = 0; w < 8; ++w) v2 += ssq[w][k];
    float vn = sqrtf(v2);
    float den = fmaxf(vn, 1e-12f);
    float cr = vn / den; cr *= cr;
    float g = wave_sum64(cr);
    scal[k] = 1.f / (den * fmaxf(sqrtf(g), 1e-12f));
  }
  __syncthreads();
  float* ob = out + (size_t)n * 32768 + c;
  #pragma unroll
  for (int k = 0; k < 64; ++k) ob[(size_t)k * 512] = val[k] * scal[k];
}

extern "C" void kernel_launch(void* const* d_in, const int* in_sizes, int n_in,
                              void* d_out, int out_size, void* d_ws, size_t ws_size,
                              hipStream_t stream) {
  const float* x     = (const float*)d_in[0];
  const float* t     = (const float*)d_in[1];
  const float* cent  = (const float*)d_in[2];
  const float* convw = (const float*)d_in[3];
  const float* convb = (const float*)d_in[4];
  const float* lnw   = (const float*)d_in[5];
  const float* lnb   = (const float*)d_in[6];
  const float* w_t   = (const float*)d_in[7];
  const float* b_t   = (const float*)d_in[8];
  const float* w_s   = (const float*)d_in[9];
  const float* b_s   = (const float*)d_in[10];
  const float* w_m   = (const float*)d_in[11];
  const float* b_m   = (const float*)d_in[12];
  const float* w_l   = (const float*)d_in[13];
  const float* b_l   = (const float*)d_in[14];
  const float* accw  = (const float*)d_in[15];
  const float* accb  = (const float*)d_in[16];
  float* ws  = (float*)d_ws;
  float* out = (float*)d_out;

  float* rn     = ws + OFF_RN;
  float* wbs    = ws + OFF_WBS;
  float* wbm    = ws + OFF_WBM;
  float* wbl    = ws + OFF_WBL;
  float* wbt    = ws + OFF_WBT;
  float* beta   = ws + OFF_BETA;
  float* P      = ws + OFF_P;
  float* Q      = ws + OFF_Q;
  float* cwpart = ws + OFF_CWPART;
  float* wr     = ws + OFF_WR;
  float* wsumb  = ws + OFF_WSUM;

  k_wbar<<<dim3(406), dim3(256), 0, stream>>>(w_s, w_m, w_l, w_t, accw, accb,
                                              b_s, b_m, b_l, b_t,
                                              wbs, wbm, wbl, wbt, beta);
  k_rn<<<dim3(512), dim3(256), 0, stream>>>(x, rn);
  k_buildP<<<dim3(4802), dim3(256), 0, stream>>>(wbs, wbm, wbl, wbt, P, Q);
  k_cw<<<dim3(1024), dim3(256), 0, stream>>>(x, t, lnw, lnb, P, Q, cwpart);
  k_logits<<<dim3(512), dim3(256), 0, stream>>>(x, convw, convb, rn, cwpart, beta, wr, wsumb);
  k_vlad<<<dim3(512), dim3(512), 0, stream>>>(x, wr, wsumb, cent, out);
}

// Round 4
// 365.071 us; speedup vs baseline: 1.3740x; 1.2516x over previous
//
#include <hip/hip_runtime.h>
#include <cstdint>
#include <cstddef>

// ReweightVLAD on MI355X — CRN collapsed to cw = xn·P + t·Q + beta with
// P,Q [C*49,49] built per call; softmax-VLAD fp32.
// Round 4: k_logits phase-1 flipped (lane=s, coalesced x loads, acc[64] over k,
// wT[c][64] transposed weights -> 4x s_load_dwordx16/channel), rn fused into
// k_logits (k_rn deleted), wr padded to stride 64 for aligned scalar batches
// in k_vlad. WR aliases the dead P/Q region.

#define N_  512
#define C_  512
#define K_  64
#define S_  49
#define CS_ 25088   // C_*S_

// ---- ws layout (float offsets) ----
#define OFF_WBS     0u
#define OFF_WBM     4608u
#define OFF_WBL     29696u
#define OFF_WBT     71168u
#define OFF_BETA    103936u
#define OFF_WT      103952u      // 64x512 transposed conv_w: wT[c*64+k]
#define OFF_P       136720u      // 1229312
#define OFF_Q       1366032u     // 1229312
#define OFF_WR      136720u      // aliases P/Q (dead after k_cw); 512*64*64
#define OFF_CWPART  2595344u     // 256*512*49
#define OFF_WSUM    9017872u
// total = 9050640 floats = 36.2 MB

__device__ __forceinline__ float wave_sum64(float v) {
  #pragma unroll
  for (int off = 32; off; off >>= 1) v += __shfl_xor(v, off, 64);
  return v;
}

// bilinear align_corners 7->20 matrix entry
__device__ __forceinline__ float m20val(int r, int p) {
  float pos = (float)(r * 6) / 19.0f;
  int lo = (int)floorf(pos);
  int hi = min(lo + 1, 6);
  float fr = pos - (float)lo;
  float v = 0.f;
  if (p == lo) v += 1.f - fr;
  if (p == hi) v += fr;
  return v;
}

// -------- 1. fold acc_w into conv weights; beta scalar --------
__global__ void k_wbar(const float* __restrict__ w_s, const float* __restrict__ w_m,
                       const float* __restrict__ w_l, const float* __restrict__ w_t,
                       const float* __restrict__ accw, const float* __restrict__ accb,
                       const float* __restrict__ b_s, const float* __restrict__ b_m,
                       const float* __restrict__ b_l, const float* __restrict__ b_t,
                       float* __restrict__ wbs, float* __restrict__ wbm,
                       float* __restrict__ wbl, float* __restrict__ wbt,
                       float* __restrict__ beta) {
  int id = blockIdx.x * 256 + threadIdx.x;      // [0, 103936) exact
  if (id == 0) {
    float b = accb[0];
    for (int o = 0; o < 32; ++o) b = fmaf(accw[o],      b_s[o], b);
    for (int o = 0; o < 32; ++o) b = fmaf(accw[32 + o], b_m[o], b);
    for (int o = 0; o < 20; ++o) b = fmaf(accw[64 + o], b_l[o], b);
    for (int o = 0; o < 16; ++o) b = fmaf(accw[84 + o], b_t[o], b);
    beta[0] = b;
  }
  if (id < 4608) {                 // xs 3x3
    int c = id / 9, uv = id % 9;
    float a = 0.f;
    for (int o = 0; o < 32; ++o) a = fmaf(accw[o], w_s[(size_t)(o * 512 + c) * 9 + uv], a);
    wbs[id] = a;
  } else if (id < 29696) {         // xm 7x7
    int i2 = id - 4608; int c = i2 / 49, uv = i2 % 49;
    float a = 0.f;
    for (int o = 0; o < 32; ++o) a = fmaf(accw[32 + o], w_m[(size_t)(o * 512 + c) * 49 + uv], a);
    wbm[i2] = a;
  } else if (id < 71168) {         // xl 9x9
    int i2 = id - 29696; int c = i2 / 81, uv = i2 % 81;
    float a = 0.f;
    for (int o = 0; o < 20; ++o) a = fmaf(accw[64 + o], w_l[(size_t)(o * 512 + c) * 81 + uv], a);
    wbl[i2] = a;
  } else {                         // tc 8x8
    int i2 = id - 71168; int c = i2 / 64, uv = i2 % 64;
    float a = 0.f;
    for (int o = 0; o < 16; ++o) a = fmaf(accw[84 + o], w_t[(size_t)(o * 512 + c) * 64 + uv], a);
    wbt[i2] = a;
  }
}

// -------- 2. transpose conv_w [64][512] -> wT [512][64] --------
__global__ void k_wt(const float* __restrict__ convw, float* __restrict__ wT) {
  int id = blockIdx.x * 256 + threadIdx.x;   // [0, 32768)
  int k = id & 63, c = id >> 6;
  wT[id] = convw[(size_t)k * 512 + c];
}

// -------- 3. build P[c,s,s'] and Q[c,s,s'] --------
__global__ void k_buildP(const float* __restrict__ wbs, const float* __restrict__ wbm,
                         const float* __restrict__ wbl, const float* __restrict__ wbt,
                         float* __restrict__ P, float* __restrict__ Q) {
  __shared__ float M[20][7];
  int t = threadIdx.x;
  if (t < 140) { int r = t / 7, p = t % 7; M[r][p] = m20val(r, p); }
  __syncthreads();
  int idx = blockIdx.x * 256 + t;               // [0, 1229312) exact
  int sp = idx % 49; int rest = idx / 49; int s = rest % 49; int c = rest / 49;
  int i = sp / 7, j = sp % 7, pp = s / 7, qq = s % 7;

  float sumP = 0.f;
  { // xs: 3x3, stride 3, pad 1
    float rv[3];
    #pragma unroll
    for (int v = 0; v < 3; ++v) { int col = j * 3 - 1 + v; rv[v] = ((unsigned)col < 20u) ? M[col][qq] : 0.f; }
    const float* wb = wbs + c * 9;
    #pragma unroll
    for (int u = 0; u < 3; ++u) {
      int row = i * 3 - 1 + u; float ru = ((unsigned)row < 20u) ? M[row][pp] : 0.f;
      float a = wb[u * 3 + 0] * rv[0];
      a = fmaf(wb[u * 3 + 1], rv[1], a);
      a = fmaf(wb[u * 3 + 2], rv[2], a);
      sumP = fmaf(ru, a, sumP);
    }
  }
  { // xm: 7x7, stride 5, pad 9
    float rv[7];
    #pragma unroll
    for (int v = 0; v < 7; ++v) { int col = j * 5 - 9 + v; rv[v] = ((unsigned)col < 20u) ? M[col][qq] : 0.f; }
    const float* wb = wbm + c * 49;
    #pragma unroll
    for (int u = 0; u < 7; ++u) {
      int row = i * 5 - 9 + u; float ru = ((unsigned)row < 20u) ? M[row][pp] : 0.f;
      float a = 0.f;
      #pragma unroll
      for (int v = 0; v < 7; ++v) a = fmaf(wb[u * 7 + v], rv[v], a);
      sumP = fmaf(ru, a, sumP);
    }
  }
  { // xl: 9x9, stride 2, pad 1
    float rv[9];
    #pragma unroll
    for (int v = 0; v < 9; ++v) { int col = j * 2 - 1 + v; rv[v] = ((unsigned)col < 20u) ? M[col][qq] : 0.f; }
    const float* wb = wbl + c * 81;
    #pragma unroll
    for (int u = 0; u < 9; ++u) {
      int row = i * 2 - 1 + u; float ru = ((unsigned)row < 20u) ? M[row][pp] : 0.f;
      float a = 0.f;
      #pragma unroll
      for (int v = 0; v < 9; ++v) a = fmaf(wb[u * 9 + v], rv[v], a);
      sumP = fmaf(ru, a, sumP);
    }
  }
  P[idx] = sumP;

  float sumQ = 0.f;
  { // tc: 8x8, stride 2, pad 0
    float rv[8];
    #pragma unroll
    for (int v = 0; v < 8; ++v) { int col = j * 2 + v; rv[v] = ((unsigned)col < 20u) ? M[col][qq] : 0.f; }
    const float* wb = wbt + c * 64;
    #pragma unroll
    for (int u = 0; u < 8; ++u) {
      int row = i * 2 + u; float ru = ((unsigned)row < 20u) ? M[row][pp] : 0.f;
      float a = 0.f;
      #pragma unroll
      for (int v = 0; v < 8; ++v) a = fmaf(wb[u * 8 + v], rv[v], a);
      sumQ = fmaf(ru, a, sumQ);
    }
  }
  Q[idx] = sumQ;
}

// -------- 4. cw split-K GEMM with inline LN stats; q-split x2 --------
// grid 1024: ks = bx&255 (x:0-127 c-quads, t:128-255), qh = (bx>>8)&1, nt = bx>>9
__global__ void __launch_bounds__(256) k_cw(
    const float* __restrict__ x, const float* __restrict__ tin,
    const float* __restrict__ lnw, const float* __restrict__ lnb,
    const float* __restrict__ P, const float* __restrict__ Q,
    float* __restrict__ cwpart) {
  int bx = blockIdx.x;
  int ks = bx & 255, qh = (bx >> 8) & 1, nt = bx >> 9;
  int n = nt * 256 + threadIdx.x;
  bool isT = ks >= 128;
  int c0 = (ks & 127) * 4;
  const float* src = isT ? tin : x;
  const float* mat = isT ? Q : P;
  int q0 = qh * 24;     // q in [0,25) or [24,49); q=24 written twice, identical bits

  float acc[25];
  #pragma unroll
  for (int i = 0; i < 25; ++i) acc[i] = 0.f;

  for (int ci = 0; ci < 4; ++ci) {
    int c = c0 + ci;
    const float* xp = src + (size_t)n * CS_ + (size_t)c * 49;
    const float* prow = mat + (size_t)c * 2401 + q0;
    if (!isT) {
      float s1 = 0.f, s2 = 0.f;
      #pragma unroll
      for (int s = 0; s < 49; ++s) { float v = xp[s]; s1 += v; s2 = fmaf(v, v, s2); }
      float m = s1 * (1.f / 49.f);
      float var = s2 * (1.f / 49.f) - m * m;
      float r = 1.f / sqrtf(var + 1e-5f);
      #pragma unroll 7
      for (int s = 0; s < 49; ++s) {
        float xv = fmaf((xp[s] - m) * r, lnw[s], lnb[s]);
        const float* pr = prow + s * 49;
        #pragma unroll
        for (int i = 0; i < 25; ++i) acc[i] = fmaf(xv, pr[i], acc[i]);
      }
    } else {
      #pragma unroll 7
      for (int s = 0; s < 49; ++s) {
        float xv = xp[s];
        const float* pr = prow + s * 49;
        #pragma unroll
        for (int i = 0; i < 25; ++i) acc[i] = fmaf(xv, pr[i], acc[i]);
      }
    }
  }
  float* o = cwpart + ((size_t)ks * 512 + n) * 49 + q0;
  #pragma unroll
  for (int i = 0; i < 25; ++i) o[i] = acc[i];
}

// -------- 5. logits + softmax + reweight + inline rn (block=n) --------
// phase 1: lane=s (coalesced x), acc[64] over k, wT uniform s_load_dwordx16.
__global__ void __launch_bounds__(256) k_logits(
    const float* __restrict__ x, const float* __restrict__ wT,
    const float* __restrict__ convb, const float* __restrict__ cwpart,
    const float* __restrict__ beta, float* __restrict__ wr,
    float* __restrict__ wsum) {
  __shared__ float part[4][64][49];     // 50176 B; flat-reused for wsum staging
  __shared__ float sqp[4][49];
  __shared__ float cw4[4 * 49];
  __shared__ float mx4[4 * 49];
  __shared__ float sm4[4 * 49];
  int n = blockIdx.x;
  int tid = threadIdx.x;
  int wu = __builtin_amdgcn_readfirstlane((int)(threadIdx.x >> 6));
  int lane = tid & 63;
  int sl = min(lane, 48);
  float* pf = &part[0][0][0];

  // phase 0: cw split-K reduction (196 threads, coalesced rows)
  if (tid < 196) {
    int s = tid % 49, g = tid / 49;
    const float* cp = cwpart + (size_t)(g * 64) * 25088 + (size_t)n * 49 + s;
    float a = 0.f;
    #pragma unroll 8
    for (int i = 0; i < 64; ++i) a += cp[(size_t)i * 25088];
    cw4[g * 49 + s] = a;
  }

  // phase 1: logits GEMM; wave wu covers c in [wu*128, wu*128+128)
  float acc[64];
  #pragma unroll
  for (int k = 0; k < 64; ++k) acc[k] = 0.f;
  float ssq = 0.f;
  const float* xb = x + (size_t)n * CS_ + (size_t)wu * (128 * 49);
  const float* wb = wT + wu * (128 * 64);
  #pragma unroll 1
  for (int c = 0; c < 128; ++c) {
    float xv = xb[c * 49 + sl];            // per-lane coalesced
    ssq = fmaf(xv, xv, ssq);
    const float* wrow = wb + c * 64;       // wave-uniform -> s_load_dwordx16 x4
    #pragma unroll
    for (int k = 0; k < 64; ++k) acc[k] = fmaf(wrow[k], xv, acc[k]);
  }
  if (lane < 49) {
    sqp[wu][lane] = ssq;
    #pragma unroll
    for (int k = 0; k < 64; ++k) part[wu][k][lane] = acc[k];
  }
  __syncthreads();

  // phase 2: softmax over k, thread = (sg, s), 16 k's each
  float lg[16];
  int sg = tid / 49, s_ = tid % 49;
  float rnv = 0.f;
  if (tid < 196) {
    float sumsq = sqp[0][s_] + sqp[1][s_] + sqp[2][s_] + sqp[3][s_];
    rnv = 1.f / fmaxf(sqrtf(sumsq), 1e-12f);
    float mloc = -1e30f;
    #pragma unroll
    for (int kk = 0; kk < 16; ++kk) {
      int kq = sg * 16 + kk;
      float a = part[0][kq][s_] + part[1][kq][s_] + part[2][kq][s_] + part[3][kq][s_];
      lg[kk] = fmaf(a, rnv, convb[kq]);
      mloc = fmaxf(mloc, lg[kk]);
    }
    mx4[sg * 49 + s_] = mloc;
  }
  __syncthreads();
  if (tid < 196) {
    float m0 = fmaxf(fmaxf(mx4[s_], mx4[49 + s_]), fmaxf(mx4[98 + s_], mx4[147 + s_]));
    float sloc = 0.f;
    #pragma unroll
    for (int kk = 0; kk < 16; ++kk) { lg[kk] = expf(lg[kk] - m0); sloc += lg[kk]; }
    sm4[sg * 49 + s_] = sloc;
  }
  __syncthreads();
  if (tid < 196) {
    float ssum = sm4[s_] + sm4[49 + s_] + sm4[98 + s_] + sm4[147 + s_];
    float cwv = cw4[s_] + cw4[49 + s_] + cw4[98 + s_] + cw4[147 + s_] + beta[0];
    float inv = cwv / ssum;        // wv = e * (cw/sum)
    float wrs = inv * rnv;
    #pragma unroll
    for (int kk = 0; kk < 16; ++kk) {
      int kq = sg * 16 + kk;
      wr[((size_t)n * 64 + kq) * 64 + s_] = lg[kk] * wrs;  // stride-64 padded rows
      pf[kq * 49 + s_] = lg[kk] * inv;                     // wsp for wsum
    }
  }
  __syncthreads();
  if (tid < 64) {
    float a = 0.f;
    #pragma unroll 7
    for (int s = 0; s < 49; ++s) a += pf[tid * 49 + s];
    wsum[n * 64 + tid] = a;
  }
}

// -------- 6. VLAD + intra-norm + global-norm, single output write --------
__global__ void __launch_bounds__(512, 2) k_vlad(
    const float* __restrict__ x, const float* __restrict__ wr,
    const float* __restrict__ wsum, const float* __restrict__ cent,
    float* __restrict__ out) {
  __shared__ float ssq[8][64];
  __shared__ float scal[64];
  int n = blockIdx.x;
  int c = threadIdx.x;                 // 0..511
  int wv = c >> 6, lane = c & 63;
  const float* xp = x + (size_t)n * CS_ + (size_t)c * 49;
  float xr[49];
  #pragma unroll
  for (int s = 0; s < 49; ++s) xr[s] = xp[s];
  const float* wrb = wr + (size_t)n * 4096;    // stride-64 rows, 256B aligned
  const float* wsb = wsum + n * 64;
  const float* cb = cent + c;

  float val[64];
  #pragma unroll
  for (int k = 0; k < 64; ++k) {
    const float* wp = wrb + k * 64;            // wave-uniform -> s_load batches
    float d0 = 0.f, d1 = 0.f, d2 = 0.f, d3 = 0.f;
    #pragma unroll
    for (int s = 0; s < 48; s += 4) {
      d0 = fmaf(wp[s],     xr[s],     d0);
      d1 = fmaf(wp[s + 1], xr[s + 1], d1);
      d2 = fmaf(wp[s + 2], xr[s + 2], d2);
      d3 = fmaf(wp[s + 3], xr[s + 3], d3);
    }
    d0 = fmaf(wp[48], xr[48], d0);
    float v = (d0 + d1) + (d2 + d3);
    val[k] = fmaf(-cb[(size_t)k * 512], wsb[k], v);
  }
  #pragma unroll
  for (int k = 0; k < 64; ++k) {
    float r2 = wave_sum64(val[k] * val[k]);
    if (lane == 0) ssq[wv][k] = r2;
  }
  __syncthreads();
  if (threadIdx.x < 64) {
    int k = threadIdx.x;
    float v2 = 0.f;
    #pragma unroll
    for (int w = 0; w < 8; ++w) v2 += ssq[w][k];
    float vn = sqrtf(v2);
    float den = fmaxf(vn, 1e-12f);
    float cr = vn / den; cr *= cr;
    float g = wave_sum64(cr);
    scal[k] = 1.f / (den * fmaxf(sqrtf(g), 1e-12f));
  }
  __syncthreads();
  float* ob = out + (size_t)n * 32768 + c;
  #pragma unroll
  for (int k = 0; k < 64; ++k) ob[(size_t)k * 512] = val[k] * scal[k];
}

extern "C" void kernel_launch(void* const* d_in, const int* in_sizes, int n_in,
                              void* d_out, int out_size, void* d_ws, size_t ws_size,
                              hipStream_t stream) {
  const float* x     = (const float*)d_in[0];
  const float* t     = (const float*)d_in[1];
  const float* cent  = (const float*)d_in[2];
  const float* convw = (const float*)d_in[3];
  const float* convb = (const float*)d_in[4];
  const float* lnw   = (const float*)d_in[5];
  const float* lnb   = (const float*)d_in[6];
  const float* w_t   = (const float*)d_in[7];
  const float* b_t   = (const float*)d_in[8];
  const float* w_s   = (const float*)d_in[9];
  const float* b_s   = (const float*)d_in[10];
  const float* w_m   = (const float*)d_in[11];
  const float* b_m   = (const float*)d_in[12];
  const float* w_l   = (const float*)d_in[13];
  const float* b_l   = (const float*)d_in[14];
  const float* accw  = (const float*)d_in[15];
  const float* accb  = (const float*)d_in[16];
  float* ws  = (float*)d_ws;
  float* out = (float*)d_out;

  float* wbs    = ws + OFF_WBS;
  float* wbm    = ws + OFF_WBM;
  float* wbl    = ws + OFF_WBL;
  float* wbt    = ws + OFF_WBT;
  float* beta   = ws + OFF_BETA;
  float* wT     = ws + OFF_WT;
  float* P      = ws + OFF_P;
  float* Q      = ws + OFF_Q;
  float* wr     = ws + OFF_WR;      // aliases P/Q — only valid after k_cw
  float* cwpart = ws + OFF_CWPART;
  float* wsumb  = ws + OFF_WSUM;

  k_wbar<<<dim3(406), dim3(256), 0, stream>>>(w_s, w_m, w_l, w_t, accw, accb,
                                              b_s, b_m, b_l, b_t,
                                              wbs, wbm, wbl, wbt, beta);
  k_wt<<<dim3(128), dim3(256), 0, stream>>>(convw, wT);
  k_buildP<<<dim3(4802), dim3(256), 0, stream>>>(wbs, wbm, wbl, wbt, P, Q);
  k_cw<<<dim3(1024), dim3(256), 0, stream>>>(x, t, lnw, lnb, P, Q, cwpart);
  k_logits<<<dim3(512), dim3(256), 0, stream>>>(x, wT, convb, cwpart, beta, wr, wsumb);
  k_vlad<<<dim3(512), dim3(512), 0, stream>>>(x, wr, wsumb, cent, out);
}